// Round 2
// baseline (443.126 us; speedup 1.0000x reference)
//
#include <hip/hip_runtime.h>
#include <hip/hip_fp16.h>
#include <stdint.h>

typedef unsigned int   uint32;
typedef unsigned short ushort_t;
typedef _Float16 half8   __attribute__((ext_vector_type(8)));
typedef float    floatx4 __attribute__((ext_vector_type(4)));

#define DEVINL __device__ __forceinline__

#define HSTR 264   // h stride (256+8 pad), x2 bytes = 528, 16B-aligned rows
#define XSTR 72    // xyz-posenc stride (64 + 8 pad)
#define DSTR 40    // dir-posenc stride (32 + 8 pad)
#define ROWS 128   // rows per block (128: halves per-CU L2 weight traffic via
                   // twin-wave L1 dedup vs the 64-row layout)
#define SMEM_BYTES ((ROWS*HSTR + ROWS*XSTR + ROWS*DSTR) * 2)   // 96256
#define N_FRAGS 1172            // total 1KB weight fragments (16x16x32 layout)

// Packed f16 weight fragments in module-owned device memory (d_ws too small;
// round 1: OOB d_ws writes corrupt the harness's pristine copies). Rewritten
// every launch from restored fp32 inputs -> graph-capture safe. L2-resident.
__device__ __align__(16) ushort_t g_ws[(size_t)N_FRAGS * 512];

DEVINL ushort_t f2h_u(float v) { return __half_as_ushort(__float2half(v)); }

// lgkm-only barrier: __syncthreads() drains vmcnt(0) too, killing any global
// weight prefetch at every layer boundary. Correctness here only needs the
// LDS drain (no cross-wave communication through global memory).
DEVINL void bar_lgkm() {
    asm volatile("s_waitcnt lgkmcnt(0)" ::: "memory");
    __builtin_amdgcn_s_barrier();
}

// ---------------------------------------------------------------------------
// 16x16x32 A-operand fragment: lane L (q=L>>4, cc=L&15) holds
// W[k = kt*32 + q*8 + j][n = nt*16 + cc], j=0..7, packed as 4 dwords.
// skip63 (layer-4 concat): k<63 -> row k, k==63 -> 0, k>63 -> row k-1.
// ---------------------------------------------------------------------------
DEVINL uint4 make_frag_qword(const float* __restrict__ W, int Kr, int Nr,
                             int skip63, int kt, int nt, int q, int cc)
{
    const int n = nt*16 + cc;
    uint32 pk[4];
    #pragma unroll
    for (int jj = 0; jj < 4; ++jj) {
        ushort_t h2[2];
        #pragma unroll
        for (int e = 0; e < 2; ++e) {
            const int k = kt*32 + q*8 + jj*2 + e;
            float v = 0.f;
            if (n < Nr) {
                if (skip63) {
                    if (k != 63) { const int rr = (k < 63) ? k : (k - 1); v = W[(size_t)rr*Nr + n]; }
                } else if (k < Kr) {
                    v = W[(size_t)k*Nr + n];
                }
            }
            h2[e] = f2h_u(v);
        }
        pk[jj] = (uint32)h2[0] | ((uint32)h2[1] << 16);
    }
    return make_uint4(pk[0], pk[1], pk[2], pk[3]);
}

// Tables via compile-time compare chain + uniform switch (no runtime-indexed
// local arrays -> no scratch).
__global__ __launch_bounds__(256) void prep_weights(
    const float* __restrict__ w0, const float* __restrict__ w1,
    const float* __restrict__ w2, const float* __restrict__ w3,
    const float* __restrict__ w4, const float* __restrict__ w5,
    const float* __restrict__ w6, const float* __restrict__ w7,
    const float* __restrict__ wf, const float* __restrict__ wsig,
    const float* __restrict__ wr1, const float* __restrict__ wr2)
{
    int gid  = blockIdx.x * 256 + threadIdx.x;
    int frag = gid >> 6;
    if (frag >= N_FRAGS) return;
    int lane = gid & 63;

    constexpr int foff[13] = {0,32,160,288,416,576,704,832,960,1088,1096,1168,1172};
    int t = 0;
    #pragma unroll
    for (int i = 1; i <= 11; ++i) if (frag >= foff[i]) t = i;

    const float* W; int fo, ntc, Kr, Nr;
    switch (t) {
        case 0:  W = w0;   fo = 0;    ntc = 16; Kr = 63;  Nr = 256; break;
        case 1:  W = w1;   fo = 32;   ntc = 16; Kr = 256; Nr = 256; break;
        case 2:  W = w2;   fo = 160;  ntc = 16; Kr = 256; Nr = 256; break;
        case 3:  W = w3;   fo = 288;  ntc = 16; Kr = 256; Nr = 256; break;
        case 4:  W = w4;   fo = 416;  ntc = 16; Kr = 319; Nr = 256; break;
        case 5:  W = w5;   fo = 576;  ntc = 16; Kr = 256; Nr = 256; break;
        case 6:  W = w6;   fo = 704;  ntc = 16; Kr = 256; Nr = 256; break;
        case 7:  W = w7;   fo = 832;  ntc = 16; Kr = 256; Nr = 256; break;
        case 8:  W = wf;   fo = 960;  ntc = 16; Kr = 256; Nr = 256; break;
        case 9:  W = wsig; fo = 1088; ntc = 1;  Kr = 256; Nr = 1;   break;
        case 10: W = wr1;  fo = 1096; ntc = 8;  Kr = 283; Nr = 128; break;
        default: W = wr2;  fo = 1168; ntc = 1;  Kr = 128; Nr = 3;   break;
    }
    int fl = frag - fo;
    int nt = fl % ntc;
    int kt = fl / ntc;
    uint4 pk = make_frag_qword(W, Kr, Nr, (t == 4) ? 1 : 0, kt, nt,
                               lane >> 4, lane & 15);
    *(uint4*)(g_ws + (size_t)frag*512 + lane*8) = pk;
}

// ---------------------------------------------------------------------------
// A-fragment load: NT_W consecutive 1KB fragments at k-tile kt.
// ---------------------------------------------------------------------------
template <int NT_W, int NTT>
DEVINL void loadA(const ushort_t* __restrict__ wsrc, int kt, int nt_lo, int lane,
                  half8 (&dst)[4])
{
    const ushort_t* wb = wsrc + (size_t)(kt*NTT + nt_lo)*512 + (size_t)lane*8;
    #pragma unroll
    for (int nt = 0; nt < NT_W; ++nt)
        dst[nt] = *(const half8*)(wb + nt*512);
}

// ---------------------------------------------------------------------------
// Layer: D[n][m] = sum_k W[k][n] * h[m][k]. A-frags from L2/L1-hot g_ws at
// prefetch depth-2 (3 rotating slots, statically indexed); B-frags from LDS
// at depth-1. NPRE: slots 0..NPRE-1 preloaded by the caller (cross-barrier
// prefetch; vmem survives bar_lgkm). First kt uses binit (bias) as C-operand.
// Twin waves (w, w+4) issue identical wsrc addresses in lockstep -> the
// second hits L1, halving per-CU L2 weight bandwidth.
// ---------------------------------------------------------------------------
template <int NT_W, int KT, int KT_SPLIT, int NTT, int S0, int S1, int NPRE>
DEVINL void run_layer(const ushort_t* __restrict__ wsrc,
                      const ushort_t* __restrict__ in0,
                      const ushort_t* __restrict__ in1,
                      int lane, int q, int cc, int nt_lo,
                      const floatx4 (&binit)[NT_W], floatx4 (&acc)[4][NT_W],
                      half8 (&afr)[3][4])
{
    half8 bfr[2][4];

    auto loadB = [&](int kt, int buf) {
        #pragma unroll
        for (int rt = 0; rt < 4; ++rt) {
            const ushort_t* p = (kt < KT_SPLIT)
                ? in0 + (rt*16 + cc)*S0 + kt*32 + q*8
                : in1 + (rt*16 + cc)*S1 + (kt - KT_SPLIT)*32 + q*8;
            bfr[buf][rt] = *(const half8*)p;
        }
    };

    if (NPRE < 1) loadA<NT_W,NTT>(wsrc, 0, nt_lo, lane, afr[0]);
    if (KT > 1 && NPRE < 2) loadA<NT_W,NTT>(wsrc, 1, nt_lo, lane, afr[1]);
    loadB(0, 0);
    #pragma unroll
    for (int kt = 0; kt < KT; ++kt) {
        if (kt + 1 < KT) loadB(kt + 1, (kt + 1) & 1);
        if (kt + 2 < KT) loadA<NT_W,NTT>(wsrc, kt + 2, nt_lo, lane, afr[(kt + 2) % 3]);
        #pragma unroll
        for (int nt = 0; nt < NT_W; ++nt)
            #pragma unroll
            for (int rt = 0; rt < 4; ++rt)
                acc[rt][nt] = __builtin_amdgcn_mfma_f32_16x16x32_f16(
                    afr[kt % 3][nt], bfr[kt & 1][rt],
                    (kt == 0) ? binit[nt] : acc[rt][nt], 0, 0, 0);
    }
}

// epilogue: optional relu, pack to f16 (cvt_pkrtz), 8B LDS store per (rt,nt).
// D layout: m = rt*16 + (lane&15), features n..n+3 = (nt_lo+nt)*16 + q*4 + reg
template <int NT_W, bool RELU>
DEVINL void epilogue_h(floatx4 (&acc)[4][NT_W], int nt_lo,
                       ushort_t* __restrict__ shh, int q, int cc)
{
    #pragma unroll
    for (int rt = 0; rt < 4; ++rt) {
        const int m = rt*16 + cc;
        #pragma unroll
        for (int nt = 0; nt < NT_W; ++nt) {
            const int n = (nt_lo + nt)*16 + q*4;
            floatx4 v = acc[rt][nt];
            if (RELU) {
                v.x = fmaxf(v.x, 0.f); v.y = fmaxf(v.y, 0.f);
                v.z = fmaxf(v.z, 0.f); v.w = fmaxf(v.w, 0.f);
            }
            uint2 u;
            u.x = __builtin_bit_cast(uint32, __builtin_amdgcn_cvt_pkrtz(v.x, v.y));
            u.y = __builtin_bit_cast(uint32, __builtin_amdgcn_cvt_pkrtz(v.z, v.w));
            *(uint2*)(shh + (size_t)m*HSTR + n) = u;
        }
    }
}

// 512 threads, 128 rows/block: 8 waves = 2 row-halves x 4 n-slices.
// (512,2): 2 waves/SIMD -> 256-VGPR cap; demand ~190 (acc 64 + afr 48 +
// bfr 32 + bl 16 + addr) -> no spill (round-1's 168-cap spill: 294MB
// scratch writes). 1 block/CU, dynamic LDS 96KB.
__global__ __launch_bounds__(512, 2) void nerf_fused(
    const float* __restrict__ x,
    const float* __restrict__ b0, const float* __restrict__ b1,
    const float* __restrict__ b2, const float* __restrict__ b3,
    const float* __restrict__ b4, const float* __restrict__ b5,
    const float* __restrict__ b6, const float* __restrict__ b7,
    const float* __restrict__ bf, const float* __restrict__ bsig,
    const float* __restrict__ br1, const float* __restrict__ br2,
    float* __restrict__ out)
{
    extern __shared__ __align__(16) ushort_t smem[];
    ushort_t* shh = smem;                               // [128][HSTR] f16 acts
    ushort_t* shx = smem + ROWS*HSTR;                   // [128][XSTR] xyz posenc
    ushort_t* shd = smem + ROWS*HSTR + ROWS*XSTR;       // [128][DSTR] dir posenc

    const int tid  = threadIdx.x;
    const int wave = tid >> 6, lane = tid & 63;
    const int w4 = wave & 3;                 // n-slice index
    const int rowoff = (wave >> 2) * 64;     // row-half offset
    const int q = lane >> 4, cc = lane & 15;
    const int r0 = blockIdx.x * ROWS;
    const ushort_t* ws = g_ws;
    const int nt_lo4 = w4 * 4;

    // row-half-local views (each wave only touches its 64 rows)
    ushort_t* shh_w = shh + rowoff*HSTR;
    ushort_t* shx_w = shx + rowoff*XSTR;
    ushort_t* shd_w = shd + rowoff*DSTR;

    // ---- layer-0 weight+bias prefetch: L2 latency hides under posenc trig.
    half8 afr[3][4];
    loadA<4,16>(ws, 0, nt_lo4, lane, afr[0]);
    loadA<4,16>(ws, 1, nt_lo4, lane, afr[1]);
    floatx4 bl[4];
    #pragma unroll
    for (int nt = 0; nt < 4; ++nt)
        bl[nt] = *(const floatx4*)(b0 + (nt_lo4 + nt)*16 + q*4);

    // ---- positional encoding (row = rowoff+lane, job-set = w4) ----
    {
        const int r = rowoff + lane;
        const float* xr = x + (size_t)(r0 + r)*6;
        for (int j = w4; j < 42; j += 4) {
            if (j < 30) {               // xyz: F=10, layout 3 + f*6 + s*3 + a
                int f = j/3, a = j%3;
                float v = xr[a] * (float)(1 << f);
                shx[r*XSTR + 3 + f*6 + a]     = f2h_u(sinf(v));
                shx[r*XSTR + 3 + f*6 + 3 + a] = f2h_u(cosf(v));
            } else {                    // dir: F=4
                int jj = j - 30, f = jj/3, a = jj%3;
                float v = xr[3+a] * (float)(1 << f);
                shd[r*DSTR + 3 + f*6 + a]     = f2h_u(sinf(v));
                shd[r*DSTR + 3 + f*6 + 3 + a] = f2h_u(cosf(v));
            }
        }
        if (w4 == 0) {                  // waves 0 and 4: one per row-half
            #pragma unroll
            for (int a = 0; a < 3; ++a) {
                shx[r*XSTR + a] = f2h_u(xr[a]);
                shd[r*DSTR + a] = f2h_u(xr[3+a]);
            }
            shx[r*XSTR + 63] = 0;                       // k-pad must be 0
            #pragma unroll
            for (int kq = 27; kq < 32; ++kq) shd[r*DSTR + kq] = 0;
        }
    }
    bar_lgkm();

    const float* BS[8] = {b0,b1,b2,b3,b4,b5,b6,b7};
    const int WO[8] = {0,16384,81920,147456,212992,294912,360448,425984};
    const floatx4 vz = {0.f, 0.f, 0.f, 0.f};

    floatx4 acc[4][4];

    // layer 0: 64(xyz) -> 256  (A kt0/kt1 + bias already in flight)
    run_layer<4,2,2,16,XSTR,XSTR,2>(ws + WO[0], shx_w, shx_w, lane, q, cc, nt_lo4, bl, acc, afr);
    // prefetch layer 1 A/bias across the barriers (bar_lgkm keeps vmcnt live)
    loadA<4,16>(ws + WO[1], 0, nt_lo4, lane, afr[0]);
    loadA<4,16>(ws + WO[1], 1, nt_lo4, lane, afr[1]);
    #pragma unroll
    for (int nt = 0; nt < 4; ++nt)
        bl[nt] = *(const floatx4*)(b1 + (nt_lo4 + nt)*16 + q*4);
    bar_lgkm();
    epilogue_h<4,true>(acc, nt_lo4, shh_w, q, cc);
    bar_lgkm();

    // layers 1..7 (layer 4 = skip-concat: 2 kt from xyz, 8 kt from h)
    #pragma unroll
    for (int l = 1; l < 8; ++l) {
        if (l == 4)
            run_layer<4,10,2,16,XSTR,HSTR,2>(ws + WO[4], shx_w, shh_w, lane, q, cc, nt_lo4, bl, acc, afr);
        else
            run_layer<4,8,8,16,HSTR,HSTR,2>(ws + WO[l], shh_w, shh_w, lane, q, cc, nt_lo4, bl, acc, afr);
        // prefetch next layer (l<7) or the final 256->256 layer (l==7)
        const ushort_t* nw = (l < 7) ? ws + WO[l+1] : ws + 491520;
        const float*    nb = (l < 7) ? BS[l+1] : bf;
        loadA<4,16>(nw, 0, nt_lo4, lane, afr[0]);
        loadA<4,16>(nw, 1, nt_lo4, lane, afr[1]);
        #pragma unroll
        for (int nt = 0; nt < 4; ++nt)
            bl[nt] = *(const floatx4*)(nb + (nt_lo4 + nt)*16 + q*4);
        bar_lgkm();   // all waves done reading shh before epilogue overwrites
        epilogue_h<4,true>(acc, nt_lo4, shh_w, q, cc);
        bar_lgkm();   // epilogue visible before next layer reads
    }

    // sigma head: waves 0,4 (one per row-half), barrier-free region that
    // overlaps the other waves' final layer. Twin waves read the same sigma
    // weights -> L1. Separate fragment slots keep afr's final-prefetch live.
    if (w4 == 0) {
        half8 hfr[3][4];
        floatx4 sacc[4][1];
        const floatx4 bz[1] = {vz};
        run_layer<1,8,8,1,HSTR,HSTR,0>(ws + 557056, shh_w, shh_w, lane, q, cc, 0, bz, sacc, hfr);
        if (q == 0) {                  // feature 0 lives in reg 0 of quad 0
            const float bs_ = bsig[0];
            #pragma unroll
            for (int rt = 0; rt < 4; ++rt)
                out[(size_t)(r0 + rowoff + rt*16 + cc)*4 + 3] = sacc[rt][0].x + bs_;
        }
    }

    // final: 256 -> 256, NO relu (barrier also covers in-flight sigma reads)
    run_layer<4,8,8,16,HSTR,HSTR,2>(ws + 491520, shh_w, shh_w, lane, q, cc, nt_lo4, bl, acc, afr);
    // prefetch rgb1 (NTT=8, per-wave 2 n-tiles)
    loadA<2,8>(ws + 561152, 0, w4*2, lane, afr[0]);
    loadA<2,8>(ws + 561152, 1, w4*2, lane, afr[1]);
    floatx4 bl2[2];
    #pragma unroll
    for (int nt = 0; nt < 2; ++nt)
        bl2[nt] = *(const floatx4*)(br1 + (w4*2 + nt)*16 + q*4);
    bar_lgkm();
    epilogue_h<4,false>(acc, nt_lo4, shh_w, q, cc);
    bar_lgkm();

    // rgb1: [final(256) | dir(27->32)] -> 128, relu
    {
        floatx4 racc[4][2];
        run_layer<2,9,8,8,HSTR,DSTR,2>(ws + 561152, shh_w, shd_w, lane, q, cc, w4*2, bl2, racc, afr);
        bar_lgkm();
        epilogue_h<2,true>(racc, w4*2, shh_w, q, cc);
        bar_lgkm();
    }

    // rgb2: 128 -> 3, sigmoid, store rgb (waves 0,4)
    if (w4 == 0) {
        half8 hfr[3][4];
        floatx4 cacc[4][1];
        const floatx4 bz[1] = {vz};
        run_layer<1,4,4,1,HSTR,HSTR,0>(ws + 598016, shh_w, shh_w, lane, q, cc, 0, bz, cacc, hfr);
        if (q == 0) {
            const float c0 = br2[0], c1 = br2[1], c2 = br2[2];
            #pragma unroll
            for (int rt = 0; rt < 4; ++rt) {
                const size_t o = (size_t)(r0 + rowoff + rt*16 + cc)*4;
                out[o+0] = 1.f/(1.f + expf(-(cacc[rt][0].x + c0)));
                out[o+1] = 1.f/(1.f + expf(-(cacc[rt][0].y + c1)));
                out[o+2] = 1.f/(1.f + expf(-(cacc[rt][0].z + c2)));
            }
        }
    }
}

extern "C" void kernel_launch(void* const* d_in, const int* in_sizes, int n_in,
                              void* d_out, int out_size, void* d_ws, size_t ws_size,
                              hipStream_t stream)
{
    const float* x  = (const float*)d_in[0];
    const float* w0 = (const float*)d_in[1];  const float* b0 = (const float*)d_in[2];
    const float* w1 = (const float*)d_in[3];  const float* b1 = (const float*)d_in[4];
    const float* w2 = (const float*)d_in[5];  const float* b2 = (const float*)d_in[6];
    const float* w3 = (const float*)d_in[7];  const float* b3 = (const float*)d_in[8];
    const float* w4 = (const float*)d_in[9];  const float* b4 = (const float*)d_in[10];
    const float* w5 = (const float*)d_in[11]; const float* b5 = (const float*)d_in[12];
    const float* w6 = (const float*)d_in[13]; const float* b6 = (const float*)d_in[14];
    const float* w7 = (const float*)d_in[15]; const float* b7 = (const float*)d_in[16];
    const float* wf = (const float*)d_in[17]; const float* bf = (const float*)d_in[18];
    const float* wsg= (const float*)d_in[19]; const float* bsg= (const float*)d_in[20];
    const float* wr1= (const float*)d_in[21]; const float* br1= (const float*)d_in[22];
    const float* wr2= (const float*)d_in[23]; const float* br2= (const float*)d_in[24];
    float* out = (float*)d_out;
    const int N = in_sizes[0] / 6;

    // one-time: allow 96KB dynamic LDS (static __shared__ caps at 64KB).
    // hipFuncSetAttribute is not a stream op; first (verification) call runs
    // outside graph capture.
    static int s_attr = 0;
    if (!s_attr) {
        hipFuncSetAttribute((const void*)nerf_fused,
                            hipFuncAttributeMaxDynamicSharedMemorySize,
                            SMEM_BYTES);
        s_attr = 1;
    }

    prep_weights<<<(N_FRAGS*64 + 255)/256, 256, 0, stream>>>(
        w0,w1,w2,w3,w4,w5,w6,w7,wf,wsg,wr1,wr2);
    nerf_fused<<<N/ROWS, 512, SMEM_BYTES, stream>>>(
        x, b0,b1,b2,b3,b4,b5,b6,b7, bf,bsg, br1,br2, out);
}

// Round 3
// 387.620 us; speedup vs baseline: 1.1432x; 1.1432x over previous
//
#include <hip/hip_runtime.h>
#include <hip/hip_fp16.h>
#include <stdint.h>

typedef unsigned int   uint32;
typedef unsigned short ushort_t;
typedef _Float16 half8   __attribute__((ext_vector_type(8)));
typedef float    floatx4 __attribute__((ext_vector_type(4)));

#define DEVINL __device__ __forceinline__

#define HSTR 264   // h stride (256+8 pad), x2 bytes = 528, 16B-aligned rows
#define XSTR 72    // xyz-posenc stride (64 + 8 pad)
#define DSTR 40    // dir-posenc stride (32 + 8 pad)
#define N_FRAGS 1172            // total 1KB weight fragments (16x16x32 layout)

// Packed f16 weight fragments in module-owned device memory. Rewritten every
// launch from restored fp32 inputs -> graph-capture safe. L2-resident.
__device__ __align__(16) ushort_t g_ws[(size_t)N_FRAGS * 512];

DEVINL ushort_t f2h_u(float v) { return __half_as_ushort(__float2half(v)); }

// lgkm-only barrier: __syncthreads() lowers to s_waitcnt vmcnt(0) lgkmcnt(0)
// + s_barrier, draining the global weight-prefetch queue at all 21 layer
// boundaries. Correctness only needs the LDS drain: every cross-wave value
// (shh/shx/shd) moves through DS ops. Global out-writes are per-wave
// exclusive. "memory" clobber: no loads/stores migrate across.
DEVINL void bar_lgkm() {
    asm volatile("s_waitcnt lgkmcnt(0)" ::: "memory");
    __builtin_amdgcn_s_barrier();
}

// ---------------------------------------------------------------------------
// 16x16x32 A-operand fragment: lane L (q=L>>4, cc=L&15) holds
// W[k = kt*32 + q*8 + j][n = nt*16 + cc], j=0..7, packed as 4 dwords.
// skip63 (layer-4 concat): k<63 -> row k, k==63 -> 0, k>63 -> row k-1.
// ---------------------------------------------------------------------------
DEVINL uint4 make_frag_qword(const float* __restrict__ W, int Kr, int Nr,
                             int skip63, int kt, int nt, int q, int cc)
{
    const int n = nt*16 + cc;
    uint32 pk[4];
    #pragma unroll
    for (int jj = 0; jj < 4; ++jj) {
        ushort_t h2[2];
        #pragma unroll
        for (int e = 0; e < 2; ++e) {
            const int k = kt*32 + q*8 + jj*2 + e;
            float v = 0.f;
            if (n < Nr) {
                if (skip63) {
                    if (k != 63) { const int rr = (k < 63) ? k : (k - 1); v = W[(size_t)rr*Nr + n]; }
                } else if (k < Kr) {
                    v = W[(size_t)k*Nr + n];
                }
            }
            h2[e] = f2h_u(v);
        }
        pk[jj] = (uint32)h2[0] | ((uint32)h2[1] << 16);
    }
    return make_uint4(pk[0], pk[1], pk[2], pk[3]);
}

// Tables via compile-time compare chain + uniform switch (no runtime-indexed
// local arrays -> no scratch).
__global__ __launch_bounds__(256) void prep_weights(
    const float* __restrict__ w0, const float* __restrict__ w1,
    const float* __restrict__ w2, const float* __restrict__ w3,
    const float* __restrict__ w4, const float* __restrict__ w5,
    const float* __restrict__ w6, const float* __restrict__ w7,
    const float* __restrict__ wf, const float* __restrict__ wsig,
    const float* __restrict__ wr1, const float* __restrict__ wr2)
{
    int gid  = blockIdx.x * 256 + threadIdx.x;
    int frag = gid >> 6;
    if (frag >= N_FRAGS) return;
    int lane = gid & 63;

    constexpr int foff[13] = {0,32,160,288,416,576,704,832,960,1088,1096,1168,1172};
    int t = 0;
    #pragma unroll
    for (int i = 1; i <= 11; ++i) if (frag >= foff[i]) t = i;

    const float* W; int fo, ntc, Kr, Nr;
    switch (t) {
        case 0:  W = w0;   fo = 0;    ntc = 16; Kr = 63;  Nr = 256; break;
        case 1:  W = w1;   fo = 32;   ntc = 16; Kr = 256; Nr = 256; break;
        case 2:  W = w2;   fo = 160;  ntc = 16; Kr = 256; Nr = 256; break;
        case 3:  W = w3;   fo = 288;  ntc = 16; Kr = 256; Nr = 256; break;
        case 4:  W = w4;   fo = 416;  ntc = 16; Kr = 319; Nr = 256; break;
        case 5:  W = w5;   fo = 576;  ntc = 16; Kr = 256; Nr = 256; break;
        case 6:  W = w6;   fo = 704;  ntc = 16; Kr = 256; Nr = 256; break;
        case 7:  W = w7;   fo = 832;  ntc = 16; Kr = 256; Nr = 256; break;
        case 8:  W = wf;   fo = 960;  ntc = 16; Kr = 256; Nr = 256; break;
        case 9:  W = wsig; fo = 1088; ntc = 1;  Kr = 256; Nr = 1;   break;
        case 10: W = wr1;  fo = 1096; ntc = 8;  Kr = 283; Nr = 128; break;
        default: W = wr2;  fo = 1168; ntc = 1;  Kr = 128; Nr = 3;   break;
    }
    int fl = frag - fo;
    int nt = fl % ntc;
    int kt = fl / ntc;
    uint4 pk = make_frag_qword(W, Kr, Nr, (t == 4) ? 1 : 0, kt, nt,
                               lane >> 4, lane & 15);
    *(uint4*)(g_ws + (size_t)frag*512 + lane*8) = pk;
}

// ---------------------------------------------------------------------------
// A-fragment load: NT_W consecutive 1KB fragments at k-tile kt.
// ---------------------------------------------------------------------------
template <int NT_W, int NTT>
DEVINL void loadA(const ushort_t* __restrict__ wsrc, int kt, int nt_lo, int lane,
                  half8 (&dst)[4])
{
    const ushort_t* wb = wsrc + (size_t)(kt*NTT + nt_lo)*512 + (size_t)lane*8;
    #pragma unroll
    for (int nt = 0; nt < NT_W; ++nt)
        dst[nt] = *(const half8*)(wb + nt*512);
}

// ---------------------------------------------------------------------------
// Layer: D[n][m] = sum_k W[k][n] * h[m][k]. A-frags direct from L2-hot g_ws,
// B-frags from LDS; both depth-1 pipelined (round-0 structure; depth-2 spilt
// at the 168-reg cap, round 1). afr is caller-owned so slot 0 can be
// prefetched across the preceding barriers (NPRE=1): bar_lgkm keeps those
// vmem loads in flight. First kt uses binit (bias) as the MFMA C-operand.
// ---------------------------------------------------------------------------
template <int NT_W, int KT, int KT_SPLIT, int NTT, int S0, int S1, int NPRE>
DEVINL void run_layer(const ushort_t* __restrict__ wsrc,
                      const ushort_t* __restrict__ in0,
                      const ushort_t* __restrict__ in1,
                      int lane, int q, int cc, int nt_lo,
                      const floatx4 (&binit)[NT_W], floatx4 (&acc)[4][NT_W],
                      half8 (&afr)[2][4])
{
    half8 bfr[2][4];

    auto loadB = [&](int kt, int buf) {
        #pragma unroll
        for (int rt = 0; rt < 4; ++rt) {
            const ushort_t* p = (kt < KT_SPLIT)
                ? in0 + (rt*16 + cc)*S0 + kt*32 + q*8
                : in1 + (rt*16 + cc)*S1 + (kt - KT_SPLIT)*32 + q*8;
            bfr[buf][rt] = *(const half8*)p;
        }
    };

    if (NPRE < 1) loadA<NT_W,NTT>(wsrc, 0, nt_lo, lane, afr[0]);
    loadB(0, 0);
    #pragma unroll
    for (int kt = 0; kt < KT; ++kt) {
        if (kt + 1 < KT) {
            loadB(kt + 1, (kt + 1) & 1);
            loadA<NT_W,NTT>(wsrc, kt + 1, nt_lo, lane, afr[(kt + 1) & 1]);
        }
        #pragma unroll
        for (int nt = 0; nt < NT_W; ++nt)
            #pragma unroll
            for (int rt = 0; rt < 4; ++rt)
                acc[rt][nt] = __builtin_amdgcn_mfma_f32_16x16x32_f16(
                    afr[kt & 1][nt], bfr[kt & 1][rt],
                    (kt == 0) ? binit[nt] : acc[rt][nt], 0, 0, 0);
    }
}

// epilogue: optional relu, pack to f16 (cvt_pkrtz), 8B LDS store per (rt,nt).
// D layout: m = rt*16 + (lane&15), features n..n+3 = (nt_lo+nt)*16 + q*4 + reg
template <int NT_W, bool RELU>
DEVINL void epilogue_h(floatx4 (&acc)[4][NT_W], int nt_lo,
                       ushort_t* __restrict__ shh, int q, int cc)
{
    #pragma unroll
    for (int rt = 0; rt < 4; ++rt) {
        const int m = rt*16 + cc;
        #pragma unroll
        for (int nt = 0; nt < NT_W; ++nt) {
            const int n = (nt_lo + nt)*16 + q*4;
            floatx4 v = acc[rt][nt];
            if (RELU) {
                v.x = fmaxf(v.x, 0.f); v.y = fmaxf(v.y, 0.f);
                v.z = fmaxf(v.z, 0.f); v.w = fmaxf(v.w, 0.f);
            }
            uint2 u;
            u.x = __builtin_bit_cast(uint32, __builtin_amdgcn_cvt_pkrtz(v.x, v.y));
            u.y = __builtin_bit_cast(uint32, __builtin_amdgcn_cvt_pkrtz(v.z, v.w));
            *(uint2*)(shh + (size_t)m*HSTR + n) = u;
        }
    }
}

// (256,3): 168-reg/wave cap; demand = round-0's 148 (84 arch + 64 acc) + 16
// for the cross-barrier slot-0 prefetch = 164 -> fits. 3 blocks/CU: the
// inter-block overlap is this kernel's latency hiding (round 2 proved it).
__global__ __launch_bounds__(256, 3) void nerf_fused(
    const float* __restrict__ x,
    const float* __restrict__ b0, const float* __restrict__ b1,
    const float* __restrict__ b2, const float* __restrict__ b3,
    const float* __restrict__ b4, const float* __restrict__ b5,
    const float* __restrict__ b6, const float* __restrict__ b7,
    const float* __restrict__ bf, const float* __restrict__ bsig,
    const float* __restrict__ br1, const float* __restrict__ br2,
    float* __restrict__ out)
{
    __shared__ __align__(16) ushort_t shh[64*HSTR];   // activations, f16
    __shared__ __align__(16) ushort_t shx[64*XSTR];   // xyz posenc (63+pad)
    __shared__ __align__(16) ushort_t shd[64*DSTR];   // dir posenc (27+pad)

    const int tid  = threadIdx.x;
    const int wave = tid >> 6, lane = tid & 63;
    const int q = lane >> 4, cc = lane & 15;
    const int r0 = blockIdx.x * 64;
    const ushort_t* ws = g_ws;
    const int nt_lo4 = wave * 4;

    // layer-0 A kt=0 prefetch: L2 latency hides under posenc trig + barrier.
    half8 afr[2][4];
    loadA<4,16>(ws, 0, nt_lo4, lane, afr[0]);

    // ---- positional encoding (row = lane, job-set = wave) ----
    {
        const int r = lane;
        const float* xr = x + (size_t)(r0 + r)*6;
        for (int j = wave; j < 42; j += 4) {
            if (j < 30) {               // xyz: F=10, layout 3 + f*6 + s*3 + a
                int f = j/3, a = j%3;
                float v = xr[a] * (float)(1 << f);
                shx[r*XSTR + 3 + f*6 + a]     = f2h_u(sinf(v));
                shx[r*XSTR + 3 + f*6 + 3 + a] = f2h_u(cosf(v));
            } else {                    // dir: F=4
                int jj = j - 30, f = jj/3, a = jj%3;
                float v = xr[3+a] * (float)(1 << f);
                shd[r*DSTR + 3 + f*6 + a]     = f2h_u(sinf(v));
                shd[r*DSTR + 3 + f*6 + 3 + a] = f2h_u(cosf(v));
            }
        }
        if (wave == 0) {
            #pragma unroll
            for (int a = 0; a < 3; ++a) {
                shx[r*XSTR + a] = f2h_u(xr[a]);
                shd[r*DSTR + a] = f2h_u(xr[3+a]);
            }
            shx[r*XSTR + 63] = 0;                       // k-pad must be 0
            #pragma unroll
            for (int kq = 27; kq < 32; ++kq) shd[r*DSTR + kq] = 0;
        }
    }
    bar_lgkm();

    const float* BS[8] = {b0,b1,b2,b3,b4,b5,b6,b7};
    const int WO[8] = {0,16384,81920,147456,212992,294912,360448,425984};
    const floatx4 vz = {0.f, 0.f, 0.f, 0.f};

    floatx4 acc[4][4];
    floatx4 bl[4];

    // layer 0: 64(xyz) -> 256  (A kt=0 already in flight)
    #pragma unroll
    for (int nt = 0; nt < 4; ++nt)
        bl[nt] = *(const floatx4*)(b0 + (nt_lo4 + nt)*16 + q*4);
    run_layer<4,2,2,16,XSTR,XSTR,1>(ws + WO[0], shx, shx, lane, q, cc, nt_lo4, bl, acc, afr);
    loadA<4,16>(ws + WO[1], 0, nt_lo4, lane, afr[0]);   // layer-1 kt=0 prefetch
    bar_lgkm();
    epilogue_h<4,true>(acc, nt_lo4, shh, q, cc);
    bar_lgkm();

    // layers 1..7 (layer 4 = skip-concat: 2 kt from xyz, 8 kt from h)
    #pragma unroll
    for (int l = 1; l < 8; ++l) {
        #pragma unroll
        for (int nt = 0; nt < 4; ++nt)
            bl[nt] = *(const floatx4*)(BS[l] + (nt_lo4 + nt)*16 + q*4);
        if (l == 4)
            run_layer<4,10,2,16,XSTR,HSTR,1>(ws + WO[4], shx, shh, lane, q, cc, nt_lo4, bl, acc, afr);
        else
            run_layer<4,8,8,16,HSTR,HSTR,1>(ws + WO[l], shh, shh, lane, q, cc, nt_lo4, bl, acc, afr);
        // prefetch next layer's kt=0 (l<7) or the final 256->256 layer (l==7);
        // stays in flight across both barriers (bar_lgkm leaves vmcnt alone)
        loadA<4,16>((l < 7) ? ws + WO[l+1] : ws + 491520, 0, nt_lo4, lane, afr[0]);
        bar_lgkm();   // all waves done reading shh before epilogue overwrites
        epilogue_h<4,true>(acc, nt_lo4, shh, q, cc);
        bar_lgkm();   // epilogue visible before next layer reads
    }

    // sigma head: wave 0 only (barrier-free region, overlaps others' final).
    // Own fragment slots: afr[0] holds the final-layer prefetch.
    if (wave == 0) {
        half8 hfr[2][4];
        floatx4 sacc[4][1];
        const floatx4 bz[1] = {vz};
        run_layer<1,8,8,1,HSTR,HSTR,0>(ws + 557056, shh, shh, lane, q, cc, 0, bz, sacc, hfr);
        if (q == 0) {                  // feature 0 lives in reg 0 of quad 0
            const float bs_ = bsig[0];
            #pragma unroll
            for (int rt = 0; rt < 4; ++rt)
                out[(size_t)(r0 + rt*16 + cc)*4 + 3] = sacc[rt][0].x + bs_;
        }
    }

    // final: 256 -> 256, NO relu (barrier also covers in-flight sigma reads)
    #pragma unroll
    for (int nt = 0; nt < 4; ++nt)
        bl[nt] = *(const floatx4*)(bf + (nt_lo4 + nt)*16 + q*4);
    run_layer<4,8,8,16,HSTR,HSTR,1>(ws + 491520, shh, shh, lane, q, cc, nt_lo4, bl, acc, afr);
    loadA<2,8>(ws + 561152, 0, wave*2, lane, afr[0]);   // rgb1 kt=0 prefetch
    bar_lgkm();
    epilogue_h<4,false>(acc, nt_lo4, shh, q, cc);
    bar_lgkm();

    // rgb1: [final(256) | dir(27->32)] -> 128, relu
    {
        floatx4 racc[4][2];
        floatx4 bl2[2];
        #pragma unroll
        for (int nt = 0; nt < 2; ++nt)
            bl2[nt] = *(const floatx4*)(br1 + (wave*2 + nt)*16 + q*4);
        run_layer<2,9,8,8,HSTR,DSTR,1>(ws + 561152, shh, shd, lane, q, cc, wave*2, bl2, racc, afr);
        bar_lgkm();
        epilogue_h<2,true>(racc, wave*2, shh, q, cc);
        bar_lgkm();
    }

    // rgb2: 128 -> 3, sigmoid, store rgb (wave 0 only)
    if (wave == 0) {
        half8 hfr[2][4];
        floatx4 cacc[4][1];
        const floatx4 bz[1] = {vz};
        run_layer<1,4,4,1,HSTR,HSTR,0>(ws + 598016, shh, shh, lane, q, cc, 0, bz, cacc, hfr);
        if (q == 0) {
            const float c0 = br2[0], c1 = br2[1], c2 = br2[2];
            #pragma unroll
            for (int rt = 0; rt < 4; ++rt) {
                const size_t o = (size_t)(r0 + rt*16 + cc)*4;
                out[o+0] = 1.f/(1.f + expf(-(cacc[rt][0].x + c0)));
                out[o+1] = 1.f/(1.f + expf(-(cacc[rt][0].y + c1)));
                out[o+2] = 1.f/(1.f + expf(-(cacc[rt][0].z + c2)));
            }
        }
    }
}

extern "C" void kernel_launch(void* const* d_in, const int* in_sizes, int n_in,
                              void* d_out, int out_size, void* d_ws, size_t ws_size,
                              hipStream_t stream)
{
    const float* x  = (const float*)d_in[0];
    const float* w0 = (const float*)d_in[1];  const float* b0 = (const float*)d_in[2];
    const float* w1 = (const float*)d_in[3];  const float* b1 = (const float*)d_in[4];
    const float* w2 = (const float*)d_in[5];  const float* b2 = (const float*)d_in[6];
    const float* w3 = (const float*)d_in[7];  const float* b3 = (const float*)d_in[8];
    const float* w4 = (const float*)d_in[9];  const float* b4 = (const float*)d_in[10];
    const float* w5 = (const float*)d_in[11]; const float* b5 = (const float*)d_in[12];
    const float* w6 = (const float*)d_in[13]; const float* b6 = (const float*)d_in[14];
    const float* w7 = (const float*)d_in[15]; const float* b7 = (const float*)d_in[16];
    const float* wf = (const float*)d_in[17]; const float* bf = (const float*)d_in[18];
    const float* wsg= (const float*)d_in[19]; const float* bsg= (const float*)d_in[20];
    const float* wr1= (const float*)d_in[21]; const float* br1= (const float*)d_in[22];
    const float* wr2= (const float*)d_in[23]; const float* br2= (const float*)d_in[24];
    float* out = (float*)d_out;
    const int N = in_sizes[0] / 6;

    prep_weights<<<(N_FRAGS*64 + 255)/256, 256, 0, stream>>>(
        w0,w1,w2,w3,w4,w5,w6,w7,wf,wsg,wr1,wr2);
    nerf_fused<<<N/64, 256, 0, stream>>>(
        x, b0,b1,b2,b3,b4,b5,b6,b7, bf,bsg, br1,br2, out);
}

// Round 4
// 383.966 us; speedup vs baseline: 1.1541x; 1.0095x over previous
//
#include <hip/hip_runtime.h>
#include <hip/hip_fp16.h>
#include <stdint.h>

typedef unsigned int   uint32;
typedef unsigned short ushort_t;
typedef _Float16 half8   __attribute__((ext_vector_type(8)));
typedef float    floatx4 __attribute__((ext_vector_type(4)));

#define DEVINL __device__ __forceinline__

#define N_FRAGS 1172            // total 1KB weight fragments (16x16x32 layout)

// ---------------------------------------------------------------------------
// Fragment-major LDS layout for all MFMA B-operands.
//   store[kt][rt][lane][8 halfs],  kt-block = 2048 halfs (4KB), rt = 512 halfs
// Element h[row][f] lives at lane' = ((f>>3)&3)*16 + (row&15), half j = f&7:
//   off(row,f) = (f>>5)*2048 + (row>>4)*512 + ((f>>3)&3)*128 + (row&15)*8 + (f&7)
// B-read for tile (rt,kt): lane L reads 16B at kt*4096B + rt*1024B + L*16B --
// the measured conflict-free stride-1 b128 pattern (lane i -> slot i mod 8).
// The old row-major 528B-stride layout put 8 lanes on the same 16B slot
// (8-way bank conflict, 2.9x LDS cost): the invariant 3.28e7
// SQ_LDS_BANK_CONFLICT = 19% of kernel time.
// ---------------------------------------------------------------------------
DEVINL int fragoff(int row, int f) {
    return (f >> 5)*2048 + (row >> 4)*512 + ((f >> 3) & 3)*128 + (row & 15)*8 + (f & 7);
}

// Packed f16 weight fragments in module-owned device memory. Rewritten every
// launch from restored fp32 inputs -> graph-capture safe. L2-resident.
__device__ __align__(16) ushort_t g_ws[(size_t)N_FRAGS * 512];

DEVINL ushort_t f2h_u(float v) { return __half_as_ushort(__float2half(v)); }

// ---------------------------------------------------------------------------
// 16x16x32 A-operand fragment: lane L (q=L>>4, cc=L&15) holds
// W[k = kt*32 + q*8 + j][n = nt*16 + cc], j=0..7, packed as 4 dwords.
// skip63 (layer-4 concat): k<63 -> row k, k==63 -> 0, k>63 -> row k-1.
// ---------------------------------------------------------------------------
DEVINL uint4 make_frag_qword(const float* __restrict__ W, int Kr, int Nr,
                             int skip63, int kt, int nt, int q, int cc)
{
    const int n = nt*16 + cc;
    uint32 pk[4];
    #pragma unroll
    for (int jj = 0; jj < 4; ++jj) {
        ushort_t h2[2];
        #pragma unroll
        for (int e = 0; e < 2; ++e) {
            const int k = kt*32 + q*8 + jj*2 + e;
            float v = 0.f;
            if (n < Nr) {
                if (skip63) {
                    if (k != 63) { const int rr = (k < 63) ? k : (k - 1); v = W[(size_t)rr*Nr + n]; }
                } else if (k < Kr) {
                    v = W[(size_t)k*Nr + n];
                }
            }
            h2[e] = f2h_u(v);
        }
        pk[jj] = (uint32)h2[0] | ((uint32)h2[1] << 16);
    }
    return make_uint4(pk[0], pk[1], pk[2], pk[3]);
}

// Tables via compile-time compare chain + uniform switch (no runtime-indexed
// local arrays -> no scratch).
__global__ __launch_bounds__(256) void prep_weights(
    const float* __restrict__ w0, const float* __restrict__ w1,
    const float* __restrict__ w2, const float* __restrict__ w3,
    const float* __restrict__ w4, const float* __restrict__ w5,
    const float* __restrict__ w6, const float* __restrict__ w7,
    const float* __restrict__ wf, const float* __restrict__ wsig,
    const float* __restrict__ wr1, const float* __restrict__ wr2)
{
    int gid  = blockIdx.x * 256 + threadIdx.x;
    int frag = gid >> 6;
    if (frag >= N_FRAGS) return;
    int lane = gid & 63;

    constexpr int foff[13] = {0,32,160,288,416,576,704,832,960,1088,1096,1168,1172};
    int t = 0;
    #pragma unroll
    for (int i = 1; i <= 11; ++i) if (frag >= foff[i]) t = i;

    const float* W; int fo, ntc, Kr, Nr;
    switch (t) {
        case 0:  W = w0;   fo = 0;    ntc = 16; Kr = 63;  Nr = 256; break;
        case 1:  W = w1;   fo = 32;   ntc = 16; Kr = 256; Nr = 256; break;
        case 2:  W = w2;   fo = 160;  ntc = 16; Kr = 256; Nr = 256; break;
        case 3:  W = w3;   fo = 288;  ntc = 16; Kr = 256; Nr = 256; break;
        case 4:  W = w4;   fo = 416;  ntc = 16; Kr = 319; Nr = 256; break;
        case 5:  W = w5;   fo = 576;  ntc = 16; Kr = 256; Nr = 256; break;
        case 6:  W = w6;   fo = 704;  ntc = 16; Kr = 256; Nr = 256; break;
        case 7:  W = w7;   fo = 832;  ntc = 16; Kr = 256; Nr = 256; break;
        case 8:  W = wf;   fo = 960;  ntc = 16; Kr = 256; Nr = 256; break;
        case 9:  W = wsig; fo = 1088; ntc = 1;  Kr = 256; Nr = 1;   break;
        case 10: W = wr1;  fo = 1096; ntc = 8;  Kr = 283; Nr = 128; break;
        default: W = wr2;  fo = 1168; ntc = 1;  Kr = 128; Nr = 3;   break;
    }
    int fl = frag - fo;
    int nt = fl % ntc;
    int kt = fl / ntc;
    uint4 pk = make_frag_qword(W, Kr, Nr, (t == 4) ? 1 : 0, kt, nt,
                               lane >> 4, lane & 15);
    *(uint4*)(g_ws + (size_t)frag*512 + lane*8) = pk;
}

// ---------------------------------------------------------------------------
// Layer: D[n][m] = sum_k W[k][n] * h[m][k]. A-frags direct from L2-hot g_ws,
// B-frags from fragment-major LDS (conflict-free stride-1 b128, one vaddr +
// folded immediate offsets); both depth-1 pipelined. in0/in1 split at
// KT_SPLIT handles the layer-4 / rgb1 concat inputs. First kt uses binit
// (bias) as the MFMA C-operand: no acc zero-init, no epilogue bias add.
// ---------------------------------------------------------------------------
template <int NT_W, int KT, int KT_SPLIT, int NTT>
DEVINL void run_layer(const ushort_t* __restrict__ wsrc,
                      const ushort_t* __restrict__ in0,
                      const ushort_t* __restrict__ in1,
                      int lane, int nt_lo,
                      const floatx4 (&binit)[NT_W], floatx4 (&acc)[4][NT_W])
{
    half8 bfr[2][4];
    half8 afr[2][NT_W];

    auto loadk = [&](int kt, int buf) {
        const ushort_t* bb = ((kt < KT_SPLIT) ? in0 + kt*2048
                                              : in1 + (kt - KT_SPLIT)*2048) + lane*8;
        #pragma unroll
        for (int rt = 0; rt < 4; ++rt)
            bfr[buf][rt] = *(const half8*)(bb + rt*512);
        const ushort_t* wb = wsrc + (size_t)(kt*NTT + nt_lo)*512 + lane*8;
        #pragma unroll
        for (int nt = 0; nt < NT_W; ++nt)
            afr[buf][nt] = *(const half8*)(wb + nt*512);
    };

    loadk(0, 0);
    #pragma unroll
    for (int kt = 0; kt < KT; ++kt) {
        const int cur = kt & 1;
        if (kt + 1 < KT) loadk(kt + 1, cur ^ 1);
        #pragma unroll
        for (int nt = 0; nt < NT_W; ++nt)
            #pragma unroll
            for (int rt = 0; rt < 4; ++rt)
                acc[rt][nt] = __builtin_amdgcn_mfma_f32_16x16x32_f16(
                    afr[cur][nt], bfr[cur][rt],
                    (kt == 0) ? binit[nt] : acc[rt][nt], 0, 0, 0);
    }
}

// epilogue: optional relu, pack to f16 (cvt_pkrtz), 8B LDS store per (rt,nt)
// into the fragment-major layout. Lane (q,cc) holds D[n=ng*16+q*4+r][m=rt*16+cc];
// dest lane' = ((2ng+(q>>1))&3)*16+cc, halfs j=(q&1)*4..+3 of kt-block ng>>1.
// Store op covers a contiguous 512B region -> ~2 lanes/16B slot, conflict-free.
template <int NT_W, bool RELU>
DEVINL void epilogue_h(floatx4 (&acc)[4][NT_W], int nt_lo,
                       ushort_t* __restrict__ dsth, int q, int cc)
{
    #pragma unroll
    for (int rt = 0; rt < 4; ++rt) {
        #pragma unroll
        for (int nt = 0; nt < NT_W; ++nt) {
            const int ng = nt_lo + nt;
            floatx4 v = acc[rt][nt];
            if (RELU) {
                v.x = fmaxf(v.x, 0.f); v.y = fmaxf(v.y, 0.f);
                v.z = fmaxf(v.z, 0.f); v.w = fmaxf(v.w, 0.f);
            }
            uint2 u;
            u.x = __builtin_bit_cast(uint32, __builtin_amdgcn_cvt_pkrtz(v.x, v.y));
            u.y = __builtin_bit_cast(uint32, __builtin_amdgcn_cvt_pkrtz(v.z, v.w));
            const int dst = (ng >> 1)*2048 + rt*512
                          + (((2*ng + (q >> 1)) & 3)*16 + cc)*8 + (q & 1)*4;
            *(uint2*)(dsth + dst) = u;
        }
    }
}

// (256,3): round-0 structure (3 blocks/CU inter-block overlap is the latency
// hiding -- rounds 1-3 proved the barrier/prefetch axis is a dead end).
// Only the LDS layout changed vs the 284.8us baseline.
__global__ __launch_bounds__(256, 3) void nerf_fused(
    const float* __restrict__ x,
    const float* __restrict__ b0, const float* __restrict__ b1,
    const float* __restrict__ b2, const float* __restrict__ b3,
    const float* __restrict__ b4, const float* __restrict__ b5,
    const float* __restrict__ b6, const float* __restrict__ b7,
    const float* __restrict__ bf, const float* __restrict__ bsig,
    const float* __restrict__ br1, const float* __restrict__ br2,
    float* __restrict__ out)
{
    __shared__ __align__(16) ushort_t shh[8*2048];   // h acts, frag-major, 32KB
    __shared__ __align__(16) ushort_t shx[2*2048];   // xyz posenc (64 f), 8KB
    __shared__ __align__(16) ushort_t shd[2048];     // dir posenc (32 f), 4KB

    const int tid  = threadIdx.x;
    const int wave = tid >> 6, lane = tid & 63;
    const int q = lane >> 4, cc = lane & 15;
    const int r0 = blockIdx.x * 64;
    const ushort_t* ws = g_ws;

    // ---- positional encoding (row = lane, job-set = wave) ----
    {
        const int r = lane;
        const float* xr = x + (size_t)(r0 + r)*6;
        for (int j = wave; j < 42; j += 4) {
            if (j < 30) {               // xyz: F=10, layout 3 + f*6 + s*3 + a
                int f = j/3, a = j%3;
                float v = xr[a] * (float)(1 << f);
                shx[fragoff(r, 3 + f*6 + a)]     = f2h_u(sinf(v));
                shx[fragoff(r, 3 + f*6 + 3 + a)] = f2h_u(cosf(v));
            } else {                    // dir: F=4
                int jj = j - 30, f = jj/3, a = jj%3;
                float v = xr[3+a] * (float)(1 << f);
                shd[fragoff(r, 3 + f*6 + a)]     = f2h_u(sinf(v));
                shd[fragoff(r, 3 + f*6 + 3 + a)] = f2h_u(cosf(v));
            }
        }
        if (wave == 0) {
            #pragma unroll
            for (int a = 0; a < 3; ++a) {
                shx[fragoff(r, a)] = f2h_u(xr[a]);
                shd[fragoff(r, a)] = f2h_u(xr[3+a]);
            }
            shx[fragoff(r, 63)] = 0;                    // k-pad must be 0
            #pragma unroll
            for (int kq = 27; kq < 32; ++kq) shd[fragoff(r, kq)] = 0;
        }
    }
    __syncthreads();

    const float* BS[8] = {b0,b1,b2,b3,b4,b5,b6,b7};
    const int WO[8] = {0,16384,81920,147456,212992,294912,360448,425984};
    const int nt_lo4 = wave * 4;
    const floatx4 vz = {0.f, 0.f, 0.f, 0.f};

    floatx4 acc[4][4];
    floatx4 bl[4];

    // layer 0: 64(xyz) -> 256
    #pragma unroll
    for (int nt = 0; nt < 4; ++nt)
        bl[nt] = *(const floatx4*)(b0 + (nt_lo4 + nt)*16 + q*4);
    run_layer<4,2,2,16>(ws + WO[0], shx, shx, lane, nt_lo4, bl, acc);
    epilogue_h<4,true>(acc, nt_lo4, shh, q, cc);
    __syncthreads();

    // layers 1..7 (layer 4 = skip-concat: 2 kt from xyz, 8 kt from h)
    #pragma unroll
    for (int l = 1; l < 8; ++l) {
        #pragma unroll
        for (int nt = 0; nt < 4; ++nt)
            bl[nt] = *(const floatx4*)(BS[l] + (nt_lo4 + nt)*16 + q*4);
        if (l == 4)
            run_layer<4,10,2,16>(ws + WO[4], shx, shh, lane, nt_lo4, bl, acc);
        else
            run_layer<4,8,8,16>(ws + WO[l], shh, shh, lane, nt_lo4, bl, acc);
        __syncthreads();   // all waves done reading shh before epilogue overwrites
        epilogue_h<4,true>(acc, nt_lo4, shh, q, cc);
        __syncthreads();   // epilogue visible before next layer reads
    }

    // sigma head: wave 0 only (barrier-free region, overlaps others' final)
    if (wave == 0) {
        floatx4 sacc[4][1];
        const floatx4 bz[1] = {vz};
        run_layer<1,8,8,1>(ws + 557056, shh, shh, lane, 0, bz, sacc);
        if (q == 0) {                  // feature 0 lives in reg 0 of quad 0
            const float bs_ = bsig[0];
            #pragma unroll
            for (int rt = 0; rt < 4; ++rt)
                out[(size_t)(r0 + rt*16 + cc)*4 + 3] = sacc[rt][0].x + bs_;
        }
    }

    // final: 256 -> 256, NO relu (barrier also covers in-flight sigma reads)
    #pragma unroll
    for (int nt = 0; nt < 4; ++nt)
        bl[nt] = *(const floatx4*)(bf + (nt_lo4 + nt)*16 + q*4);
    run_layer<4,8,8,16>(ws + 491520, shh, shh, lane, nt_lo4, bl, acc);
    __syncthreads();
    epilogue_h<4,false>(acc, nt_lo4, shh, q, cc);
    __syncthreads();

    // rgb1: [final(256) | dir(27->32)] -> 128, relu
    {
        floatx4 racc[4][2];
        floatx4 bl2[2];
        #pragma unroll
        for (int nt = 0; nt < 2; ++nt)
            bl2[nt] = *(const floatx4*)(br1 + (wave*2 + nt)*16 + q*4);
        run_layer<2,9,8,8>(ws + 561152, shh, shd, lane, wave*2, bl2, racc);
        __syncthreads();
        epilogue_h<2,true>(racc, wave*2, shh, q, cc);
        __syncthreads();
    }

    // rgb2: 128 -> 3, sigmoid, store rgb (wave 0 only)
    if (wave == 0) {
        floatx4 cacc[4][1];
        const floatx4 bz[1] = {vz};
        run_layer<1,4,4,1>(ws + 598016, shh, shh, lane, 0, bz, cacc);
        if (q == 0) {
            const float c0 = br2[0], c1 = br2[1], c2 = br2[2];
            #pragma unroll
            for (int rt = 0; rt < 4; ++rt) {
                const size_t o = (size_t)(r0 + rt*16 + cc)*4;
                out[o+0] = 1.f/(1.f + expf(-(cacc[rt][0].x + c0)));
                out[o+1] = 1.f/(1.f + expf(-(cacc[rt][0].y + c1)));
                out[o+2] = 1.f/(1.f + expf(-(cacc[rt][0].z + c2)));
            }
        }
    }
}

extern "C" void kernel_launch(void* const* d_in, const int* in_sizes, int n_in,
                              void* d_out, int out_size, void* d_ws, size_t ws_size,
                              hipStream_t stream)
{
    const float* x  = (const float*)d_in[0];
    const float* w0 = (const float*)d_in[1];  const float* b0 = (const float*)d_in[2];
    const float* w1 = (const float*)d_in[3];  const float* b1 = (const float*)d_in[4];
    const float* w2 = (const float*)d_in[5];  const float* b2 = (const float*)d_in[6];
    const float* w3 = (const float*)d_in[7];  const float* b3 = (const float*)d_in[8];
    const float* w4 = (const float*)d_in[9];  const float* b4 = (const float*)d_in[10];
    const float* w5 = (const float*)d_in[11]; const float* b5 = (const float*)d_in[12];
    const float* w6 = (const float*)d_in[13]; const float* b6 = (const float*)d_in[14];
    const float* w7 = (const float*)d_in[15]; const float* b7 = (const float*)d_in[16];
    const float* wf = (const float*)d_in[17]; const float* bf = (const float*)d_in[18];
    const float* wsg= (const float*)d_in[19]; const float* bsg= (const float*)d_in[20];
    const float* wr1= (const float*)d_in[21]; const float* br1= (const float*)d_in[22];
    const float* wr2= (const float*)d_in[23]; const float* br2= (const float*)d_in[24];
    float* out = (float*)d_out;
    const int N = in_sizes[0] / 6;

    prep_weights<<<(N_FRAGS*64 + 255)/256, 256, 0, stream>>>(
        w0,w1,w2,w3,w4,w5,w6,w7,wf,wsg,wr1,wr2);
    nerf_fused<<<N/64, 256, 0, stream>>>(
        x, b0,b1,b2,b3,b4,b5,b6,b7, bf,bsg, br1,br2, out);
}